// Round 12
// baseline (239.177 us; speedup 1.0000x reference)
//
#include <hip/hip_runtime.h>
#include <math.h>
#include <stdint.h>

// ---- static problem sizes ----
#define S_    32        // sentences
#define BV_   16        // videos
#define M_    128       // moments
#define C_    256       // channels
#define NN    4096      // N*N
#define P_    2080      // triu(64) count
#define BP    33280     // BV_*P_
#define NSAMP 512       // neg samples per sentence
#define CHUNK 130       // BP / 256

// ---------------- Threefry-2x32 (exact JAX replication, key=(0,42)) -------------
__device__ __forceinline__ uint32_t rotl32(uint32_t x, int n){ return (x<<n) | (x>>(32-n)); }

__device__ __forceinline__ void threefry2x32(uint32_t k0, uint32_t k1, uint32_t &x0, uint32_t &x1){
  uint32_t ks2 = k0 ^ k1 ^ 0x1BD11BDAu;
  x0 += k0; x1 += k1;
  #define TF_R(r) { x0 += x1; x1 = rotl32(x1, r); x1 ^= x0; }
  TF_R(13) TF_R(15) TF_R(26) TF_R(6)
  x0 += k1;  x1 += ks2 + 1u;
  TF_R(17) TF_R(29) TF_R(16) TF_R(24)
  x0 += ks2; x1 += k0 + 2u;
  TF_R(13) TF_R(15) TF_R(26) TF_R(6)
  x0 += k0;  x1 += k1 + 3u;
  TF_R(17) TF_R(29) TF_R(16) TF_R(24)
  x0 += k1;  x1 += ks2 + 4u;
  TF_R(13) TF_R(15) TF_R(26) TF_R(6)
  x0 += ks2; x1 += k0 + 5u;
  #undef TF_R
}

// p in [0,2080) -> triangle (i,j), exact
__device__ __forceinline__ void p_to_ij(int p, int &i, int &j){
  i = (int)((129.0f - sqrtf((float)(16641 - 8*p))) * 0.5f);
  while(64*(i+1) - ((i+1)*i)/2 <= p) ++i;
  while(64*i - (i*(i-1))/2 > p) --i;
  j = i + (p - (64*i - (i*(i-1))/2));
}

// ============== kernel 1: top-2(x4) + pos_vf + qsumT ==============================
__global__ __launch_bounds__(256) void k_prep(const float* __restrict__ iou2ds,
                                              const float* __restrict__ vfeat,
                                              float* __restrict__ pos_vf,
                                              float* __restrict__ qsumT){
  const int s = blockIdx.x;      // 32
  const int t = threadIdx.x;     // 256
  __shared__ float sv1[256], sv2[256];
  __shared__ int   si1[256], si2[256];
  __shared__ int   fpk_s[8];
  __shared__ float wsum[4];
  __shared__ float s_inv;

  for(int q=0; q<4; ++q){
    const float* row = iou2ds + (size_t)(s*4 + q)*NN;
    float v1=-1e30f, v2=-1e30f; int i1=0x7FFFFFFF, i2=0x7FFFFFFF;
    for(int f=t; f<NN; f+=256){
      int ti = f>>6, tj = f&63;
      if(tj < ti) continue;
      float v = row[f];
      if(v > v1 || (v == v1 && f < i1)){ v2=v1; i2=i1; v1=v; i1=f; }
      else if(v > v2 || (v == v2 && f < i2)){ v2=v; i2=f; }
    }
    sv1[t]=v1; sv2[t]=v2; si1[t]=i1; si2[t]=i2;
    for(int stp=128; stp>0; stp>>=1){
      __syncthreads();
      if(t < stp){
        float a1=sv1[t], a2=sv2[t]; int x1=si1[t], x2=si2[t];
        float b1=sv1[t+stp], b2=sv2[t+stp]; int y1=si1[t+stp], y2=si2[t+stp];
        float m1v, m2v; int m1i, m2i;
        bool aTop = (a1 > b1) || (a1 == b1 && x1 < y1);
        if(aTop){
          m1v=a1; m1i=x1;
          if((a2 > b1) || (a2 == b1 && x2 < y1)){ m2v=a2; m2i=x2; } else { m2v=b1; m2i=y1; }
        } else {
          m1v=b1; m1i=y1;
          if((b2 > a1) || (b2 == a1 && y2 < x1)){ m2v=b2; m2i=y2; } else { m2v=a1; m2i=x1; }
        }
        sv1[t]=m1v; sv2[t]=m2v; si1[t]=m1i; si2[t]=m2i;
      }
    }
    __syncthreads();
    if(t==0){ fpk_s[q*2+0]=si1[0]; fpk_s[q*2+1]=si2[0]; }
    __syncthreads();
  }

  float v[8];
  #pragma unroll
  for(int r=0;r<8;r++) v[r] = vfeat[((size_t)s*C_ + t)*NN + fpk_s[r]];

  float qs = 0.f;
  for(int r=0; r<8; ++r){
    float ss = v[r]*v[r];
    for(int o=32;o>0;o>>=1) ss += __shfl_down(ss, o, 64);
    if((t&63)==0) wsum[t>>6]=ss;
    __syncthreads();
    if(t==0){
      float tot = wsum[0]+wsum[1]+wsum[2]+wsum[3];
      s_inv = 1.0f / fmaxf(sqrtf(tot), 1e-12f);
    }
    __syncthreads();
    float pv = v[r] * s_inv;
    pos_vf[(size_t)(s*8+r)*C_ + t] = pv;
    qs += pv;
  }
  qsumT[t*32 + s] = qs;
}

// ============== kernel 2: norm + bank fill, float4 staging (one 67MB read) ========
// dyn LDS layout: tile[256*65] | ssp4[1024] | invs[64]  => 17728 floats = 70912 B
__global__ __launch_bounds__(256) void k_bank(const float* __restrict__ vfeat,
                                              float* __restrict__ bank){
  extern __shared__ char dyn_sm[];
  float* tile = (float*)dyn_sm;                    // [256][65]
  float* ssp4 = (float*)dyn_sm + 256*65;           // [256][4]
  float* invs = (float*)dyn_sm + 256*65 + 1024;    // [64]

  const int i = blockIdx.x;      // triangle row
  const int b = blockIdx.y;      // video
  const int t = threadIdx.x;
  const float* basep = vfeat + (size_t)(2*b)*C_*NN + (size_t)i*64;
  const int cc0 = t >> 4;        // 0..15
  const int j0  = (t & 15) * 4;  // 0..60 step 4

  float sq0=0.f, sq1=0.f, sq2=0.f, sq3=0.f;
  #pragma unroll
  for(int it=0; it<16; ++it){
    int cc = it*16 + cc0;
    float4 v = *(const float4*)(basep + (size_t)cc*NN + j0);  // 16B/lane coalesced
    tile[cc*65 + j0+0] = v.x; tile[cc*65 + j0+1] = v.y;
    tile[cc*65 + j0+2] = v.z; tile[cc*65 + j0+3] = v.w;
    sq0 += v.x*v.x; sq1 += v.y*v.y; sq2 += v.z*v.z; sq3 += v.w*v.w;
  }
  ssp4[t*4+0]=sq0; ssp4[t*4+1]=sq1; ssp4[t*4+2]=sq2; ssp4[t*4+3]=sq3;
  __syncthreads();
  if(t < 64){
    float tot = 0.f;
    #pragma unroll
    for(int g=0; g<16; ++g) tot += ssp4[g*64 + t];   // conflict-free, fixed order
    invs[t] = 1.0f/fmaxf(sqrtf(tot), 1e-12f);
  }
  __syncthreads();

  const int start = 64*i - (i*(i-1))/2;
  for(int jj=i; jj<64; ++jj){
    size_t row = (size_t)b*P_ + start + (jj - i);
    bank[row*C_ + t] = tile[t*65 + jj] * invs[jj];
  }
}

// ============== kernel 3: fused GEMM + keys (R6-proven) ===========================
__global__ __launch_bounds__(256) void k_fused_keys(const float* __restrict__ bank,
                                                    const float* __restrict__ qsumT,
                                                    const float* __restrict__ iou2d,
                                                    unsigned int* __restrict__ ukey){
  __shared__ float tile[32*257];       // [cc][j]
  const int t = threadIdx.x;
  const int j = blockIdx.x*256 + t;    // 130*256 = 33280 exactly

  int bv = j / P_;
  int p  = j - bv*P_;
  int pi, pj; p_to_ij(p, pi, pj);
  int fp = pi*64 + pj;
  float iou0 = iou2d[(size_t)(2*bv)*NN + fp];
  float iou1 = iou2d[(size_t)(2*bv+1)*NN + fp];

  float acc[32];
  #pragma unroll
  for(int s=0;s<32;s++) acc[s]=0.f;

  for(int cb=0; cb<8; ++cb){
    __syncthreads();
    #pragma unroll
    for(int it=0; it<8; ++it){
      int idx = it*256 + t;            // 0..2047 float4 units
      int jj  = idx >> 3;              // 0..255
      int c4  = idx & 7;               // 0..7
      float4 v = ((const float4*)bank)[ (size_t)(blockIdx.x*256 + jj)*64 + cb*8 + c4 ];
      tile[(c4*4+0)*257 + jj]=v.x; tile[(c4*4+1)*257 + jj]=v.y;
      tile[(c4*4+2)*257 + jj]=v.z; tile[(c4*4+3)*257 + jj]=v.w;
    }
    __syncthreads();
    const float* qb = qsumT + cb*32*32;
    #pragma unroll 2
    for(int cc=0; cc<32; ++cc){
      float v = tile[cc*257 + t];
      const float* qc = qb + cc*32;    // uniform -> scalar loads
      #pragma unroll
      for(int s=0;s<32;s++) acc[s] = fmaf(qc[s], v, acc[s]);
    }
  }

  #pragma unroll 1
  for(int s=0;s<32;s++){
    float fz = 0.0625f*acc[s] + 0.5f;
    bool pos = ((s>>1)==bv) && (((s&1)?iou1:iou0) > 0.5f);
    float val = pos ? 0.f : fz*fz;
    float key;
    if(val > 0.f){
      float logw = logf(fmaxf(val, 1e-30f));
      unsigned int f = (unsigned int)(s*BP + j);
      const unsigned int HALF = 532480u;   // (S_*BP)/2
      bool second = f >= HALF;
      uint32_t x0 = second ? (f - HALF) : f;
      uint32_t x1 = second ? f : (f + HALF);
      threefry2x32(0u, 42u, x0, x1);
      uint32_t bits = second ? x1 : x0;
      uint32_t fb = (bits >> 9) | 0x3f800000u;
      float f01 = __uint_as_float(fb) - 1.0f;
      const float mn = 1e-7f, mx = 1.0f - 1e-7f;
      float u = fmaxf(mn, f01*(mx-mn) + mn);
      float g = -logf(-logf(u));
      key = logw + g;
    } else {
      key = -INFINITY;
    }
    unsigned int kb = __float_as_uint(key);
    kb = (kb & 0x80000000u) ? ~kb : (kb | 0x80000000u);
    ukey[(size_t)s*BP + j] = kb;
  }
}

// ============== kernel 4: exact top-512, LDS row + replicated hist (R6-proven) ====
__global__ __launch_bounds__(1024) void k_select(const unsigned int* __restrict__ ukey,
                                                 int* __restrict__ neglist){
  extern __shared__ char dyn_sm[];
  unsigned int* row  = (unsigned int*)dyn_sm;        // [BP]
  unsigned int* hist = (unsigned int*)dyn_sm + BP;   // [256*17]
  int* eqbuf = (int*)hist;                           // aliased after descent
  __shared__ int s_wv[16];
  __shared__ unsigned int s_prefix;
  __shared__ int s_cntgt, s_need, s_eq;

  const int s = blockIdx.x;
  const int t = threadIdx.x;
  const int lane = t & 63;
  const int col  = t & 15;
  const unsigned int* grow = ukey + (size_t)s*BP;
  int* list = neglist + s*NSAMP;

  unsigned int prefix = 0, pmask = 0;
  int need = NSAMP, cnt_gt = 0;

  for(int lev=0; lev<4; ++lev){
    const int shift = 24 - 8*lev;
    for(int k=t; k<256*17; k+=1024) hist[k] = 0;
    __syncthreads();
    if(lev==0){
      for(int k=t; k<BP; k+=1024){
        unsigned int u = grow[k];
        row[k] = u;
        atomicAdd(&hist[(u >> 24)*17 + col], 1u);
      }
    } else {
      for(int k=t; k<BP; k+=1024){
        unsigned int u = row[k];
        if((u & pmask) == prefix)
          atomicAdd(&hist[((u >> shift) & 255u)*17 + col], 1u);
      }
    }
    __syncthreads();
    int v = 0; unsigned int h = 0;
    if(t < 256){
      const unsigned int* hr = hist + t*17;
      #pragma unroll
      for(int c=0;c<16;c++) h += hr[c];
      v = (int)h;
      #pragma unroll
      for(int off=1; off<64; off<<=1){
        int src = lane + off;
        int o = __shfl(v, (src<64)?src:lane, 64);
        v += (src<64)? o : 0;
      }
      if(lane==0) s_wv[t>>6] = v;
    }
    __syncthreads();
    if(t < 256){
      int wv4 = t>>6, tail = 0;
      for(int w2=wv4+1; w2<4; ++w2) tail += s_wv[w2];
      int Sb  = v + tail;
      int Sb1 = Sb - (int)h;
      if(Sb >= need && Sb1 < need){
        s_prefix = prefix | ((unsigned int)t << shift);
        s_cntgt  = cnt_gt + Sb1;
        s_need   = need - Sb1;
      }
    }
    __syncthreads();
    prefix = s_prefix; cnt_gt = s_cntgt; need = s_need;
    pmask |= (0xFFu << shift);
    __syncthreads();
  }

  const unsigned int ustar = prefix;
  const int quota = need;

  if(t==0) s_eq = 0;
  __syncthreads();

  int gtc = 0;
  for(int k=t; k<BP; k+=1024) gtc += (row[k] > ustar) ? 1 : 0;
  int vg = gtc;
  #pragma unroll
  for(int off=1; off<64; off<<=1){
    int src = lane - off;
    int o = __shfl(vg, (src>=0)?src:lane, 64);
    vg += (src>=0)? o : 0;
  }
  const int wv16 = t>>6;
  if(lane==63) s_wv[wv16] = vg;
  __syncthreads();
  int base2 = 0;
  for(int w2=0; w2<wv16; ++w2) base2 += s_wv[w2];
  int gi = base2 + vg - gtc;
  for(int k=t; k<BP; k+=1024){
    unsigned int u = row[k];
    if(u > ustar){
      list[gi++] = k;
    } else if(u == ustar){
      int e = atomicAdd(&s_eq, 1);
      if(e < 2048) eqbuf[e] = k;
    }
  }
  __syncthreads();
  const int eqn = s_eq;
  if(eqn <= 2048){
    for(int i2=t; i2<eqn; i2+=1024){
      int ii = eqbuf[i2];
      int r = 0;
      for(int j2=0; j2<eqn; ++j2) r += (eqbuf[j2] < ii) ? 1 : 0;
      if(r < quota) list[cnt_gt + r] = ii;
    }
  } else {
    if(t==0){                      // degenerate mass-tie fallback
      int taken = 0;
      for(int idx=0; idx<BP && taken<quota; ++idx)
        if(row[idx]==ustar){ list[cnt_gt + taken] = idx; ++taken; }
    }
  }
}

// ============== kernel 5: partial neg sums (8 blocks/sentence), fence-free ========
__global__ __launch_bounds__(512) void k_neg(const float* __restrict__ bank,
                                             const float* __restrict__ pos_vf,
                                             const int* __restrict__ neglist,
                                             float* __restrict__ ns_part){
  const int s   = blockIdx.x >> 3;
  const int oct = blockIdx.x & 7;
  const int t = threadIdx.x;     // 512
  __shared__ float pv[8][C_];

  for(int idx=t; idx<8*C_; idx+=512) pv[idx>>8][idx&255] = pos_vf[(size_t)(s*8)*C_ + idx];
  __syncthreads();

  const int a = t >> 6;          // ref 0..7 (wave index)
  const int n = t & 63;          // neg within octant (lane)
  const int j = neglist[s*NSAMP + oct*64 + n];
  const float4* bp  = (const float4*)(bank + (size_t)j*C_);
  const float4* pva = (const float4*)&pv[a][0];
  float acc = 0.f;
  #pragma unroll 8
  for(int c4=0; c4<64; ++c4){
    float4 bv = bp[c4], av = pva[c4];
    acc += bv.x*av.x + bv.y*av.y + bv.z*av.z + bv.w*av.w;
  }
  float e = expf(acc/0.1f);
  for(int o=32;o>0;o>>=1) e += __shfl_down(e, o, 64);
  if(n==0) ns_part[((s*8 + a)*8) + oct] = e;   // plain store; next dispatch reads
}

// ============== kernel 6: final loss (1 block; dispatch boundary = coherence) =====
__global__ __launch_bounds__(256) void k_fin(const float* __restrict__ pos_vf,
                                             const float* __restrict__ ns_part,
                                             float* __restrict__ out){
  const int t = threadIdx.x;     // 256 = 32 sentences x 8 refs
  __shared__ float terms[256];

  const int s2 = t>>3, a2 = t&7;
  float ns = 0.f;
  #pragma unroll
  for(int oc=0; oc<8; ++oc) ns += ns_part[t*8 + oc];

  const float4* A = (const float4*)(pos_vf + (size_t)(s2*8 + a2)*C_);
  float termSum = 0.f;
  for(int b2=0; b2<8; ++b2){
    const float4* B = (const float4*)(pos_vf + (size_t)(s2*8 + b2)*C_);
    float dot = 0.f;
    #pragma unroll 8
    for(int c4=0; c4<64; ++c4){
      float4 av = A[c4], bv = B[c4];
      dot += av.x*bv.x + av.y*bv.y + av.z*bv.z + av.w*bv.w;
    }
    float pl = dot/0.1f;
    termSum += logf(expf(pl) + ns) - pl;
  }
  terms[t] = termSum;
  __syncthreads();
  if(t==0){
    float sum = 0.f;
    for(int i2=0;i2<256;i2++) sum += terms[i2];
    float loss = sum / 2048.0f;
    out[0] = loss * 1.0f;        // WEIGHT = 1.0
    out[1] = loss;
  }
}

// ======================= host launcher =============================================
extern "C" void kernel_launch(void* const* d_in, const int* in_sizes, int n_in,
                              void* d_out, int out_size, void* d_ws, size_t ws_size,
                              hipStream_t stream) {
  const float* video_feats = (const float*)d_in[0];
  const float* iou2d  = (const float*)d_in[4];
  const float* iou2ds = (const float*)d_in[5];

  // workspace layout (bytes, 256-aligned)
  const size_t o_pvf   = 0;            // 256*256 f32 (262144)
  const size_t o_qsT   = 262144;       // 256*32 f32 (32768)
  const size_t o_bank  = 294912;       // 33280*256 f32 (34078720)
  const size_t o_ukey  = 34373632;     // 32*33280 u32 (4259840)
  const size_t o_list  = 38633472;     // 32*512 i32 (65536)
  const size_t o_nsp   = 38699008;     // 32*8*8 f32 (8192)
  const size_t NEED    = 38707200;
  if (ws_size < NEED) return;

  char* w = (char*)d_ws;
  float*        pos_vf  = (float*)(w + o_pvf);
  float*        qsumT   = (float*)(w + o_qsT);
  float*        bank    = (float*)(w + o_bank);
  unsigned int* ukey    = (unsigned int*)(w + o_ukey);
  int*          neglist = (int*)(w + o_list);
  float*        ns_part = (float*)(w + o_nsp);
  float*        out     = (float*)d_out;

  const int BK_LDS  = (256*65 + 1024 + 64) * 4;   // 70912 B: tile+ssp4+invs (recomputed!)
  const int SEL_LDS = (BP + 256*17) * 4;          // 150528
  static bool attr_set = false;
  if(!attr_set){
    (void)hipFuncSetAttribute((const void*)k_bank,
                              hipFuncAttributeMaxDynamicSharedMemorySize, BK_LDS);
    (void)hipFuncSetAttribute((const void*)k_select,
                              hipFuncAttributeMaxDynamicSharedMemorySize, SEL_LDS);
    attr_set = true;
  }

  k_prep<<<32, 256, 0, stream>>>(iou2ds, video_feats, pos_vf, qsumT);
  k_bank<<<dim3(64,16), 256, BK_LDS, stream>>>(video_feats, bank);
  k_fused_keys<<<130, 256, 0, stream>>>(bank, qsumT, iou2d, ukey);
  k_select<<<32, 1024, SEL_LDS, stream>>>(ukey, neglist);
  k_neg<<<256, 512, 0, stream>>>(bank, pos_vf, neglist, ns_part);
  k_fin<<<1, 256, 0, stream>>>(pos_vf, ns_part, out);
}

// Round 13
// 178.633 us; speedup vs baseline: 1.3389x; 1.3389x over previous
//
#include <hip/hip_runtime.h>
#include <math.h>
#include <stdint.h>

// ---- static problem sizes ----
#define S_    32        // sentences
#define BV_   16        // videos
#define M_    128       // moments
#define C_    256       // channels
#define NN    4096      // N*N
#define P_    2080      // triu(64) count
#define BP    33280     // BV_*P_
#define NSAMP 512       // neg samples per sentence
#define CHUNK 130       // BP / 256

// ---------------- Threefry-2x32 (exact JAX replication, key=(0,42)) -------------
__device__ __forceinline__ uint32_t rotl32(uint32_t x, int n){ return (x<<n) | (x>>(32-n)); }

__device__ __forceinline__ void threefry2x32(uint32_t k0, uint32_t k1, uint32_t &x0, uint32_t &x1){
  uint32_t ks2 = k0 ^ k1 ^ 0x1BD11BDAu;
  x0 += k0; x1 += k1;
  #define TF_R(r) { x0 += x1; x1 = rotl32(x1, r); x1 ^= x0; }
  TF_R(13) TF_R(15) TF_R(26) TF_R(6)
  x0 += k1;  x1 += ks2 + 1u;
  TF_R(17) TF_R(29) TF_R(16) TF_R(24)
  x0 += ks2; x1 += k0 + 2u;
  TF_R(13) TF_R(15) TF_R(26) TF_R(6)
  x0 += k0;  x1 += k1 + 3u;
  TF_R(17) TF_R(29) TF_R(16) TF_R(24)
  x0 += k1;  x1 += ks2 + 4u;
  TF_R(13) TF_R(15) TF_R(26) TF_R(6)
  x0 += ks2; x1 += k0 + 5u;
  #undef TF_R
}

// p in [0,2080) -> triangle (i,j), exact
__device__ __forceinline__ void p_to_ij(int p, int &i, int &j){
  i = (int)((129.0f - sqrtf((float)(16641 - 8*p))) * 0.5f);
  while(64*(i+1) - ((i+1)*i)/2 <= p) ++i;
  while(64*i - (i*(i-1))/2 > p) --i;
  j = i + (p - (64*i - (i*(i-1))/2));
}

// ============== kernel 1: top-2(x4) + pos_vf + qsumT ==============================
__global__ __launch_bounds__(256) void k_prep(const float* __restrict__ iou2ds,
                                              const float* __restrict__ vfeat,
                                              float* __restrict__ pos_vf,
                                              float* __restrict__ qsumT){
  const int s = blockIdx.x;      // 32
  const int t = threadIdx.x;     // 256
  __shared__ float sv1[256], sv2[256];
  __shared__ int   si1[256], si2[256];
  __shared__ int   fpk_s[8];
  __shared__ float wsum[4];
  __shared__ float s_inv;

  for(int q=0; q<4; ++q){
    const float* row = iou2ds + (size_t)(s*4 + q)*NN;
    float v1=-1e30f, v2=-1e30f; int i1=0x7FFFFFFF, i2=0x7FFFFFFF;
    for(int f=t; f<NN; f+=256){
      int ti = f>>6, tj = f&63;
      if(tj < ti) continue;
      float v = row[f];
      if(v > v1 || (v == v1 && f < i1)){ v2=v1; i2=i1; v1=v; i1=f; }
      else if(v > v2 || (v == v2 && f < i2)){ v2=v; i2=f; }
    }
    sv1[t]=v1; sv2[t]=v2; si1[t]=i1; si2[t]=i2;
    for(int stp=128; stp>0; stp>>=1){
      __syncthreads();
      if(t < stp){
        float a1=sv1[t], a2=sv2[t]; int x1=si1[t], x2=si2[t];
        float b1=sv1[t+stp], b2=sv2[t+stp]; int y1=si1[t+stp], y2=si2[t+stp];
        float m1v, m2v; int m1i, m2i;
        bool aTop = (a1 > b1) || (a1 == b1 && x1 < y1);
        if(aTop){
          m1v=a1; m1i=x1;
          if((a2 > b1) || (a2 == b1 && x2 < y1)){ m2v=a2; m2i=x2; } else { m2v=b1; m2i=y1; }
        } else {
          m1v=b1; m1i=y1;
          if((b2 > a1) || (b2 == a1 && y2 < x1)){ m2v=b2; m2i=y2; } else { m2v=a1; m2i=x1; }
        }
        sv1[t]=m1v; sv2[t]=m2v; si1[t]=m1i; si2[t]=m2i;
      }
    }
    __syncthreads();
    if(t==0){ fpk_s[q*2+0]=si1[0]; fpk_s[q*2+1]=si2[0]; }
    __syncthreads();
  }

  float v[8];
  #pragma unroll
  for(int r=0;r<8;r++) v[r] = vfeat[((size_t)s*C_ + t)*NN + fpk_s[r]];

  float qs = 0.f;
  for(int r=0; r<8; ++r){
    float ss = v[r]*v[r];
    for(int o=32;o>0;o>>=1) ss += __shfl_down(ss, o, 64);
    if((t&63)==0) wsum[t>>6]=ss;
    __syncthreads();
    if(t==0){
      float tot = wsum[0]+wsum[1]+wsum[2]+wsum[3];
      s_inv = 1.0f / fmaxf(sqrtf(tot), 1e-12f);
    }
    __syncthreads();
    float pv = v[r] * s_inv;
    pos_vf[(size_t)(s*8+r)*C_ + t] = pv;
    qs += pv;
  }
  qsumT[t*32 + s] = qs;
}

// ============== kernel 2: norm + bank fill, float4 staging (one 67MB read) ========
// dyn LDS layout: tile[256*65] | ssp4[1024] | invs[64]  => 17728 floats = 70912 B
__global__ __launch_bounds__(256) void k_bank(const float* __restrict__ vfeat,
                                              float* __restrict__ bank){
  extern __shared__ char dyn_sm[];
  float* tile = (float*)dyn_sm;                    // [256][65]
  float* ssp4 = (float*)dyn_sm + 256*65;           // [256][4]
  float* invs = (float*)dyn_sm + 256*65 + 1024;    // [64]

  const int i = blockIdx.x;      // triangle row
  const int b = blockIdx.y;      // video
  const int t = threadIdx.x;
  const float* basep = vfeat + (size_t)(2*b)*C_*NN + (size_t)i*64;
  const int cc0 = t >> 4;        // 0..15
  const int j0  = (t & 15) * 4;  // 0..60 step 4

  float sq0=0.f, sq1=0.f, sq2=0.f, sq3=0.f;
  #pragma unroll
  for(int it=0; it<16; ++it){
    int cc = it*16 + cc0;
    float4 v = *(const float4*)(basep + (size_t)cc*NN + j0);  // 16B/lane coalesced
    tile[cc*65 + j0+0] = v.x; tile[cc*65 + j0+1] = v.y;
    tile[cc*65 + j0+2] = v.z; tile[cc*65 + j0+3] = v.w;
    sq0 += v.x*v.x; sq1 += v.y*v.y; sq2 += v.z*v.z; sq3 += v.w*v.w;
  }
  ssp4[t*4+0]=sq0; ssp4[t*4+1]=sq1; ssp4[t*4+2]=sq2; ssp4[t*4+3]=sq3;
  __syncthreads();
  if(t < 64){
    float tot = 0.f;
    #pragma unroll
    for(int g=0; g<16; ++g) tot += ssp4[g*64 + t];   // conflict-free, fixed order
    invs[t] = 1.0f/fmaxf(sqrtf(tot), 1e-12f);
  }
  __syncthreads();

  const int start = 64*i - (i*(i-1))/2;
  for(int jj=i; jj<64; ++jj){
    size_t row = (size_t)b*P_ + start + (jj - i);
    bank[row*C_ + t] = tile[t*65 + jj] * invs[jj];
  }
}

// ============== kernel 3: fused GEMM + keys (R6-proven) ===========================
__global__ __launch_bounds__(256) void k_fused_keys(const float* __restrict__ bank,
                                                    const float* __restrict__ qsumT,
                                                    const float* __restrict__ iou2d,
                                                    unsigned int* __restrict__ ukey){
  __shared__ float tile[32*257];       // [cc][j]
  const int t = threadIdx.x;
  const int j = blockIdx.x*256 + t;    // 130*256 = 33280 exactly

  int bv = j / P_;
  int p  = j - bv*P_;
  int pi, pj; p_to_ij(p, pi, pj);
  int fp = pi*64 + pj;
  float iou0 = iou2d[(size_t)(2*bv)*NN + fp];
  float iou1 = iou2d[(size_t)(2*bv+1)*NN + fp];

  float acc[32];
  #pragma unroll
  for(int s=0;s<32;s++) acc[s]=0.f;

  for(int cb=0; cb<8; ++cb){
    __syncthreads();
    #pragma unroll
    for(int it=0; it<8; ++it){
      int idx = it*256 + t;            // 0..2047 float4 units
      int jj  = idx >> 3;              // 0..255
      int c4  = idx & 7;               // 0..7
      float4 v = ((const float4*)bank)[ (size_t)(blockIdx.x*256 + jj)*64 + cb*8 + c4 ];
      tile[(c4*4+0)*257 + jj]=v.x; tile[(c4*4+1)*257 + jj]=v.y;
      tile[(c4*4+2)*257 + jj]=v.z; tile[(c4*4+3)*257 + jj]=v.w;
    }
    __syncthreads();
    const float* qb = qsumT + cb*32*32;
    #pragma unroll 2
    for(int cc=0; cc<32; ++cc){
      float v = tile[cc*257 + t];
      const float* qc = qb + cc*32;    // uniform -> scalar loads
      #pragma unroll
      for(int s=0;s<32;s++) acc[s] = fmaf(qc[s], v, acc[s]);
    }
  }

  #pragma unroll 1
  for(int s=0;s<32;s++){
    float fz = 0.0625f*acc[s] + 0.5f;
    bool pos = ((s>>1)==bv) && (((s&1)?iou1:iou0) > 0.5f);
    float val = pos ? 0.f : fz*fz;
    float key;
    if(val > 0.f){
      float logw = logf(fmaxf(val, 1e-30f));
      unsigned int f = (unsigned int)(s*BP + j);
      const unsigned int HALF = 532480u;   // (S_*BP)/2
      bool second = f >= HALF;
      uint32_t x0 = second ? (f - HALF) : f;
      uint32_t x1 = second ? f : (f + HALF);
      threefry2x32(0u, 42u, x0, x1);
      uint32_t bits = second ? x1 : x0;
      uint32_t fb = (bits >> 9) | 0x3f800000u;
      float f01 = __uint_as_float(fb) - 1.0f;
      const float mn = 1e-7f, mx = 1.0f - 1e-7f;
      float u = fmaxf(mn, f01*(mx-mn) + mn);
      float g = -logf(-logf(u));
      key = logw + g;
    } else {
      key = -INFINITY;
    }
    unsigned int kb = __float_as_uint(key);
    kb = (kb & 0x80000000u) ? ~kb : (kb | 0x80000000u);
    ukey[(size_t)s*BP + j] = kb;
  }
}

// ============== kernel 4: exact top-512, LDS row + replicated hist (R6-proven) ====
__global__ __launch_bounds__(1024) void k_select(const unsigned int* __restrict__ ukey,
                                                 int* __restrict__ neglist){
  extern __shared__ char dyn_sm[];
  unsigned int* row  = (unsigned int*)dyn_sm;        // [BP]
  unsigned int* hist = (unsigned int*)dyn_sm + BP;   // [256*17]
  int* eqbuf = (int*)hist;                           // aliased after descent
  __shared__ int s_wv[16];
  __shared__ unsigned int s_prefix;
  __shared__ int s_cntgt, s_need, s_eq;

  const int s = blockIdx.x;
  const int t = threadIdx.x;
  const int lane = t & 63;
  const int col  = t & 15;
  const unsigned int* grow = ukey + (size_t)s*BP;
  int* list = neglist + s*NSAMP;

  unsigned int prefix = 0, pmask = 0;
  int need = NSAMP, cnt_gt = 0;

  for(int lev=0; lev<4; ++lev){
    const int shift = 24 - 8*lev;
    for(int k=t; k<256*17; k+=1024) hist[k] = 0;
    __syncthreads();
    if(lev==0){
      for(int k=t; k<BP; k+=1024){
        unsigned int u = grow[k];
        row[k] = u;
        atomicAdd(&hist[(u >> 24)*17 + col], 1u);
      }
    } else {
      for(int k=t; k<BP; k+=1024){
        unsigned int u = row[k];
        if((u & pmask) == prefix)
          atomicAdd(&hist[((u >> shift) & 255u)*17 + col], 1u);
      }
    }
    __syncthreads();
    int v = 0; unsigned int h = 0;
    if(t < 256){
      const unsigned int* hr = hist + t*17;
      #pragma unroll
      for(int c=0;c<16;c++) h += hr[c];
      v = (int)h;
      #pragma unroll
      for(int off=1; off<64; off<<=1){
        int src = lane + off;
        int o = __shfl(v, (src<64)?src:lane, 64);
        v += (src<64)? o : 0;
      }
      if(lane==0) s_wv[t>>6] = v;
    }
    __syncthreads();
    if(t < 256){
      int wv4 = t>>6, tail = 0;
      for(int w2=wv4+1; w2<4; ++w2) tail += s_wv[w2];
      int Sb  = v + tail;
      int Sb1 = Sb - (int)h;
      if(Sb >= need && Sb1 < need){
        s_prefix = prefix | ((unsigned int)t << shift);
        s_cntgt  = cnt_gt + Sb1;
        s_need   = need - Sb1;
      }
    }
    __syncthreads();
    prefix = s_prefix; cnt_gt = s_cntgt; need = s_need;
    pmask |= (0xFFu << shift);
    __syncthreads();
  }

  const unsigned int ustar = prefix;
  const int quota = need;

  if(t==0) s_eq = 0;
  __syncthreads();

  int gtc = 0;
  for(int k=t; k<BP; k+=1024) gtc += (row[k] > ustar) ? 1 : 0;
  int vg = gtc;
  #pragma unroll
  for(int off=1; off<64; off<<=1){
    int src = lane - off;
    int o = __shfl(vg, (src>=0)?src:lane, 64);
    vg += (src>=0)? o : 0;
  }
  const int wv16 = t>>6;
  if(lane==63) s_wv[wv16] = vg;
  __syncthreads();
  int base2 = 0;
  for(int w2=0; w2<wv16; ++w2) base2 += s_wv[w2];
  int gi = base2 + vg - gtc;
  for(int k=t; k<BP; k+=1024){
    unsigned int u = row[k];
    if(u > ustar){
      list[gi++] = k;
    } else if(u == ustar){
      int e = atomicAdd(&s_eq, 1);
      if(e < 2048) eqbuf[e] = k;
    }
  }
  __syncthreads();
  const int eqn = s_eq;
  if(eqn <= 2048){
    for(int i2=t; i2<eqn; i2+=1024){
      int ii = eqbuf[i2];
      int r = 0;
      for(int j2=0; j2<eqn; ++j2) r += (eqbuf[j2] < ii) ? 1 : 0;
      if(r < quota) list[cnt_gt + r] = ii;
    }
  } else {
    if(t==0){                      // degenerate mass-tie fallback
      int taken = 0;
      for(int idx=0; idx<BP && taken<quota; ++idx)
        if(row[idx]==ustar){ list[cnt_gt + taken] = idx; ++taken; }
    }
  }
}

// ============== kernel 5: neg_sum per sentence (R6-proven, pv in LDS) =============
__global__ __launch_bounds__(512) void k_negsum(const float* __restrict__ bank,
                                                const float* __restrict__ pos_vf,
                                                const int* __restrict__ neglist,
                                                float* __restrict__ ns){
  int s = blockIdx.x;
  int t = threadIdx.x;           // 512
  __shared__ float pv[8][C_];
  for(int idx=t; idx<8*C_; idx+=512) pv[idx>>8][idx&255] = pos_vf[(size_t)(s*8)*C_ + idx];
  __syncthreads();
  int j = neglist[s*NSAMP + t];
  const float4* bp = (const float4*)(bank + (size_t)j*C_);
  float acc[8] = {0,0,0,0,0,0,0,0};
  for(int c4=0; c4<64; ++c4){
    float4 bv = bp[c4];
    #pragma unroll
    for(int a=0;a<8;a++){
      const float* pva = &pv[a][c4*4];
      acc[a] += bv.x*pva[0] + bv.y*pva[1] + bv.z*pva[2] + bv.w*pva[3];
    }
  }
  float e[8];
  #pragma unroll
  for(int a=0;a<8;a++){
    float v = expf(acc[a]/0.1f);
    for(int o=32;o>0;o>>=1) v += __shfl_down(v, o, 64);
    e[a] = v;
  }
  __shared__ float red[8][8];    // [wave][a]
  int wv = t>>6;
  if((t&63)==0){
    #pragma unroll
    for(int a=0;a<8;a++) red[wv][a]=e[a];
  }
  __syncthreads();
  if(t < 8){
    float tot = 0.f;
    for(int w=0; w<8; w++) tot += red[w][t];
    ns[s*8 + t] = tot;
  }
}

// ============== kernel 6: per-sentence loss partials (R6-proven, pv in LDS) =======
__global__ __launch_bounds__(64) void k_loss(const float* __restrict__ pos_vf,
                                             const float* __restrict__ ns,
                                             float* __restrict__ partial){
  int s = blockIdx.x;
  int t = threadIdx.x;           // 64 = 8 refs x 8 pos
  __shared__ float pv[8][260];
  for(int idx=t; idx<8*C_; idx+=64){
    pv[idx>>8][idx&255] = pos_vf[(size_t)(s*8)*C_ + idx];
  }
  __syncthreads();
  int a = t>>3, b = t&7;
  float dot = 0.f;
  for(int c=0;c<C_;c++) dot += pv[a][c]*pv[b][c];
  float pl = dot/0.1f;
  float term = logf(expf(pl) + ns[s*8+a]) - pl;
  for(int o=32;o>0;o>>=1) term += __shfl_down(term, o, 64);
  if(t==0) partial[s]=term;
}

// ============== kernel 7: final reduce (R6-proven) ================================
__global__ void k_final(const float* __restrict__ partial, float* __restrict__ out){
  int t = threadIdx.x;           // 64
  float v = (t < 32) ? partial[t] : 0.f;
  for(int o=32;o>0;o>>=1) v += __shfl_down(v, o, 64);
  if(t==0){
    float loss = v / 2048.0f;
    out[0] = loss * 1.0f;        // WEIGHT = 1.0
    out[1] = loss;
  }
}

// ======================= host launcher =============================================
extern "C" void kernel_launch(void* const* d_in, const int* in_sizes, int n_in,
                              void* d_out, int out_size, void* d_ws, size_t ws_size,
                              hipStream_t stream) {
  const float* video_feats = (const float*)d_in[0];
  const float* iou2d  = (const float*)d_in[4];
  const float* iou2ds = (const float*)d_in[5];

  // workspace layout (bytes, 256-aligned)
  const size_t o_pvf   = 0;            // 256*256 f32 (262144)
  const size_t o_qsT   = 262144;       // 256*32 f32 (32768)
  const size_t o_bank  = 294912;       // 33280*256 f32 (34078720)
  const size_t o_ukey  = 34373632;     // 32*33280 u32 (4259840)
  const size_t o_list  = 38633472;     // 32*512 i32 (65536)
  const size_t o_ns    = 38699008;     // 256 f32 (1024)
  const size_t o_part  = 38700032;     // 32 f32 (128)
  const size_t NEED    = 38700288;
  if (ws_size < NEED) return;

  char* w = (char*)d_ws;
  float*        pos_vf  = (float*)(w + o_pvf);
  float*        qsumT   = (float*)(w + o_qsT);
  float*        bank    = (float*)(w + o_bank);
  unsigned int* ukey    = (unsigned int*)(w + o_ukey);
  int*          neglist = (int*)(w + o_list);
  float*        ns      = (float*)(w + o_ns);
  float*        part    = (float*)(w + o_part);
  float*        out     = (float*)d_out;

  const int BK_LDS  = (256*65 + 1024 + 64) * 4;   // 70912 B: tile+ssp4+invs
  const int SEL_LDS = (BP + 256*17) * 4;          // 150528
  static bool attr_set = false;
  if(!attr_set){
    (void)hipFuncSetAttribute((const void*)k_bank,
                              hipFuncAttributeMaxDynamicSharedMemorySize, BK_LDS);
    (void)hipFuncSetAttribute((const void*)k_select,
                              hipFuncAttributeMaxDynamicSharedMemorySize, SEL_LDS);
    attr_set = true;
  }

  k_prep<<<32, 256, 0, stream>>>(iou2ds, video_feats, pos_vf, qsumT);
  k_bank<<<dim3(64,16), 256, BK_LDS, stream>>>(video_feats, bank);
  k_fused_keys<<<130, 256, 0, stream>>>(bank, qsumT, iou2d, ukey);
  k_select<<<32, 1024, SEL_LDS, stream>>>(ukey, neglist);
  k_negsum<<<32, 512, 0, stream>>>(bank, pos_vf, neglist, ns);
  k_loss<<<32, 64, 0, stream>>>(pos_vf, ns, part);
  k_final<<<1, 64, 0, stream>>>(part, out);
}